// Round 5
// baseline (75.072 us; speedup 1.0000x reference)
//
#include <hip/hip_runtime.h>

// BPR loss: out = (2/n^2) * sum_{(i,j): t[j] > t[i]} softplus(x[i] - x[j])
//
// Exact decomposition (ties ~1 pair, <1e-7 -- ignored):
//   softplus(z) = ln(1+e^-|z|) + max(z,0) = ln(1+e^-|z|) + 0.5(z + |z|)
//   Total = sum_{unordered} ln(1+e^-|dx|)            (symmetric, target-free)
//         + sum_i x_i * (c_t[i] - c_u[i])            (linear in rank counts)
//   where c_t[i] = #{j: t_j > t_i}, c_u[i] = #{j: x_j > x_i}.
// K1 computes the linear term with a 4-VALU/pair body (no transcendentals);
// by linearity each j-chunk's partial sum folds straight into the output
// atomic -- no per-i count array needed.
// K2 computes the symmetric term over the triangle with a 5-VALU + 1-exp
// body; ln(1+e) via cubic poly in e (max err ~8e-4 ln-units, validated r4).

constexpr float LOG2E = 1.44269504088896340736f;
constexpr float C1 = 0.983568f;
constexpr float C2 = -0.397138f;
constexpr float C3 = 0.106717f;

// ---------------- K1: linear/rank term ----------------
// grid (64, 16): blockIdx.x -> i-tile of 256, blockIdx.y -> j-chunk of 1024.
__global__ __launch_bounds__(256)
void bpr_rank_kernel(const float* __restrict__ inp, const float* __restrict__ tgt,
                     float* __restrict__ out, float scale) {
    const int tid = threadIdx.x;
    const int i   = blockIdx.x * 256 + tid;
    const int jb  = blockIdx.y * 1024;

    __shared__ alignas(16) float sx[1024];
    __shared__ alignas(16) float st[1024];
    for (int k = tid; k < 1024; k += 256) {
        int g = jb + k;
        sx[k] = inp[g];
        st[k] = tgt[g];
    }
    const float x0 = inp[i];
    const float t0 = tgt[i];
    __syncthreads();

    int mt = 0, mx = 0;    // two chains to halve dependency latency
    const float4* sx4 = (const float4*)sx;
    const float4* st4 = (const float4*)st;
#pragma unroll 8
    for (int c = 0; c < 256; ++c) {
        float4 xv = sx4[c];     // uniform addr -> LDS broadcast
        float4 tv = st4[c];
        mt += (tv.x > t0); mx += (xv.x > x0);
        mt += (tv.y > t0); mx += (xv.y > x0);
        mt += (tv.z > t0); mx += (xv.z > x0);
        mt += (tv.w > t0); mx += (xv.w > x0);
    }

    float s = x0 * (float)(mt - mx);

#pragma unroll
    for (int off = 32; off > 0; off >>= 1)
        s += __shfl_down(s, off, 64);

    __shared__ float swave[4];
    if ((tid & 63) == 0) swave[tid >> 6] = s;
    __syncthreads();
    if (tid == 0)
        atomicAdd(out, (swave[0] + swave[1] + swave[2] + swave[3]) * scale);
}

// ---------------- K2: symmetric term, triangular ----------------
__global__ __launch_bounds__(256)
void bpr_sym_kernel(const float* __restrict__ inp,
                    float* __restrict__ out, int nt, float scale) {
    int bi = 0, rem = blockIdx.x;
    while (rem >= nt - bi) { rem -= nt - bi; ++bi; }
    const int bj = bi + rem;

    const int tid = threadIdx.x;

    __shared__ alignas(16) float su[256];
    su[tid] = inp[bj * 256 + tid] * LOG2E;
    const float u0 = inp[bi * 256 + tid] * LOG2E;
    __syncthreads();

    float acc = 0.0f;
    const float4* su4 = (const float4*)su;

    if (bi != bj) {
#pragma unroll 8
        for (int c = 0; c < 64; ++c) {
            float4 v = su4[c];
            {
                float d = u0 - v.x;
                float e = __builtin_amdgcn_exp2f(-__builtin_fabsf(d));
                float p = fmaf(C3, e, C2); p = fmaf(p, e, C1);
                acc = fmaf(e, p, acc);
            }
            {
                float d = u0 - v.y;
                float e = __builtin_amdgcn_exp2f(-__builtin_fabsf(d));
                float p = fmaf(C3, e, C2); p = fmaf(p, e, C1);
                acc = fmaf(e, p, acc);
            }
            {
                float d = u0 - v.z;
                float e = __builtin_amdgcn_exp2f(-__builtin_fabsf(d));
                float p = fmaf(C3, e, C2); p = fmaf(p, e, C1);
                acc = fmaf(e, p, acc);
            }
            {
                float d = u0 - v.w;
                float e = __builtin_amdgcn_exp2f(-__builtin_fabsf(d));
                float p = fmaf(C3, e, C2); p = fmaf(p, e, C1);
                acc = fmaf(e, p, acc);
            }
        }
    } else {
        // diagonal tile: pairs j > tid only; e forced to 0 kills the
        // contribution exactly (poly has no constant term).
#pragma unroll 8
        for (int j = 0; j < 256; ++j) {
            float d = u0 - su[j];
            float e = (j > tid) ? __builtin_amdgcn_exp2f(-__builtin_fabsf(d)) : 0.0f;
            float p = fmaf(C3, e, C2); p = fmaf(p, e, C1);
            acc = fmaf(e, p, acc);
        }
    }

#pragma unroll
    for (int off = 32; off > 0; off >>= 1)
        acc += __shfl_down(acc, off, 64);

    __shared__ float swave[4];
    if ((tid & 63) == 0) swave[tid >> 6] = acc;
    __syncthreads();
    if (tid == 0)
        atomicAdd(out, (swave[0] + swave[1] + swave[2] + swave[3]) * scale);
}

extern "C" void kernel_launch(void* const* d_in, const int* in_sizes, int n_in,
                              void* d_out, int out_size, void* d_ws, size_t ws_size,
                              hipStream_t stream) {
    const float* inp = (const float*)d_in[0];
    const float* tgt = (const float*)d_in[1];
    float* out = (float*)d_out;
    const int n = in_sizes[0];          // 16384

    hipMemsetAsync(out, 0, out_size * sizeof(float), stream);

    const float scale = 2.0f / ((float)n * (float)n);

    dim3 g1(n / 256, 16);               // (64, 16) = 1024 blocks
    bpr_rank_kernel<<<g1, 256, 0, stream>>>(inp, tgt, out, scale);

    const int nt = n / 256;             // 64
    bpr_sym_kernel<<<nt * (nt + 1) / 2, 256, 0, stream>>>(inp, out, nt, scale);
}

// Round 6
// 44.989 us; speedup vs baseline: 1.6687x; 1.6687x over previous
//
#include <hip/hip_runtime.h>

// BPR loss: out = (2/n^2) * sum_{(i,j): t[j] > t[i]} softplus(x[i] - x[j])
//
// softplus(z) = ln(1+e^-|z|) + max(z,0). Per unordered pair {i,j} exactly one
// direction passes the strict mask (fp32 ties ~3 pairs, <1e-7 -- ignored), and
// the passing direction's relu is max(sd,0), sd = (t_j>t_i)? d : -d with
// d = u_i - u_j, u = x*log2e (positive scale preserves order; *ln2 at end).
// The same formula evaluated from either side of the pair gives the same
// value, so one triangular visit per pair suffices.
//
// ln(1+e) with e = 2^-|d| via cubic poly in e (max err ~8e-4 ln-units).
// Body: 8 VALU + 1 v_exp_f32.
//
// Diagonal tiles run the identical full 256x256 loop: that counts each
// unordered pair twice and 256 self-pairs (e=1 -> poly(1)=P1, relu=0);
// block epilogue corrects: S = 0.5*(S - 256*P1). Branch-free inner loop.
//
// No memset/atomics: blocks plain-store partials to d_ws, 1-block reduce
// writes d_out (hipMemsetAsync cost 39us/replay as fillBufferAligned in r5).

constexpr float LOG2E = 1.44269504088896340736f;
constexpr float LN2   = 0.69314718055994530942f;
constexpr float C1 = 0.983568f;   // cubic interp of ln(1+e) at {0,1/3,2/3,1}
constexpr float C2 = -0.397138f;
constexpr float C3 = 0.106717f;
constexpr float P1 = (C3 + C2) + C1;   // poly evaluated at e=1, same fp order

__global__ __launch_bounds__(256)
void bpr_fused_kernel(const float* __restrict__ inp, const float* __restrict__ tgt,
                      float* __restrict__ ws, int nt) {
    // linear block id -> (bi, bj), upper triangle incl. diagonal
    int bi = 0, rem = blockIdx.x;
    while (rem >= nt - bi) { rem -= nt - bi; ++bi; }
    const int bj = bi + rem;

    const int tid = threadIdx.x;

    __shared__ alignas(16) float2 sj[256];
    sj[tid] = make_float2(inp[bj * 256 + tid] * LOG2E, tgt[bj * 256 + tid]);
    const float u0 = inp[bi * 256 + tid] * LOG2E;
    const float t0 = tgt[bi * 256 + tid];
    __syncthreads();

    float accL = 0.0f;   // sum poly(e) ~= sum ln(1+e^-|d|)   (ln-units)
    float accR = 0.0f;   // sum max(sd, 0)                    (u-units)
    const float4* sj4 = (const float4*)sj;   // 2 (u,t) pairs per b128 read

#pragma unroll 8
    for (int c = 0; c < 128; ++c) {
        float4 v = sj4[c];               // uniform addr -> LDS broadcast
        {
            float d  = u0 - v.x;
            float e  = __builtin_amdgcn_exp2f(-__builtin_fabsf(d));
            float p  = fmaf(e, fmaf(e, C3, C2), C1);
            accL = fmaf(e, p, accL);
            float sd = (v.y > t0) ? d : -d;
            accR = fmaxf(accR + sd, accR);      // accR += max(sd,0)
        }
        {
            float d  = u0 - v.z;
            float e  = __builtin_amdgcn_exp2f(-__builtin_fabsf(d));
            float p  = fmaf(e, fmaf(e, C3, C2), C1);
            accL = fmaf(e, p, accL);
            float sd = (v.w > t0) ? d : -d;
            accR = fmaxf(accR + sd, accR);
        }
    }

    float s = fmaf(LN2, accR, accL);     // ln-units

    // wave64 shuffle reduction
#pragma unroll
    for (int off = 32; off > 0; off >>= 1)
        s += __shfl_down(s, off, 64);

    __shared__ float swave[4];
    if ((tid & 63) == 0) swave[tid >> 6] = s;
    __syncthreads();
    if (tid == 0) {
        float S = swave[0] + swave[1] + swave[2] + swave[3];
        if (bi == bj) S = 0.5f * (S - 256.0f * P1);  // un-double + drop selfs
        ws[blockIdx.x] = S;              // plain store, no atomics
    }
}

__global__ __launch_bounds__(256)
void bpr_reduce_kernel(const float* __restrict__ ws, float* __restrict__ out,
                       int nblocks, float scale) {
    const int tid = threadIdx.x;
    float s = 0.0f;
    for (int i = tid; i < nblocks; i += 256) s += ws[i];
#pragma unroll
    for (int off = 32; off > 0; off >>= 1)
        s += __shfl_down(s, off, 64);
    __shared__ float swave[4];
    if ((tid & 63) == 0) swave[tid >> 6] = s;
    __syncthreads();
    if (tid == 0)
        out[0] = (swave[0] + swave[1] + swave[2] + swave[3]) * scale;
}

extern "C" void kernel_launch(void* const* d_in, const int* in_sizes, int n_in,
                              void* d_out, int out_size, void* d_ws, size_t ws_size,
                              hipStream_t stream) {
    const float* inp = (const float*)d_in[0];
    const float* tgt = (const float*)d_in[1];
    float* out = (float*)d_out;
    float* ws  = (float*)d_ws;
    const int n = in_sizes[0];          // 16384

    const int nt = n / 256;                      // 64
    const int nblocks = nt * (nt + 1) / 2;       // 2080
    const float scale = 2.0f / ((float)n * (float)n);

    bpr_fused_kernel<<<nblocks, 256, 0, stream>>>(inp, tgt, ws, nt);
    bpr_reduce_kernel<<<1, 256, 0, stream>>>(ws, out, nblocks, scale);
}